// Round 4
// baseline (1768.621 us; speedup 1.0000x reference)
//
#include <hip/hip_runtime.h>
#include <math.h>

// ---------------- helpers ----------------
__device__ __forceinline__ void ld16(const float* __restrict__ p, float* a) {
    const float4* q = (const float4*)p;
    float4 v0 = q[0], v1 = q[1], v2 = q[2], v3 = q[3];
    a[0]=v0.x; a[1]=v0.y; a[2]=v0.z; a[3]=v0.w;
    a[4]=v1.x; a[5]=v1.y; a[6]=v1.z; a[7]=v1.w;
    a[8]=v2.x; a[9]=v2.y; a[10]=v2.z; a[11]=v2.w;
    a[12]=v3.x; a[13]=v3.y; a[14]=v3.z; a[15]=v3.w;
}

// ---------------- CSR build ----------------
__global__ __launch_bounds__(256) void k_count(const int* __restrict__ ei, int* __restrict__ cnt, int E) {
    int e = blockIdx.x * blockDim.x + threadIdx.x;
    if (e < E) atomicAdd(&cnt[ei[E + e]], 1);
}

__global__ __launch_bounds__(256) void k_scanA(const int* __restrict__ cnt, int* __restrict__ offs,
                                               int* __restrict__ bsum, int N) {
    __shared__ int s[256];
    int i = blockIdx.x * 256 + threadIdx.x;
    int v = (i < N) ? cnt[i] : 0;
    s[threadIdx.x] = v;
    __syncthreads();
    #pragma unroll
    for (int d = 1; d < 256; d <<= 1) {
        int t = (threadIdx.x >= d) ? s[threadIdx.x - d] : 0;
        __syncthreads();
        s[threadIdx.x] += t;
        __syncthreads();
    }
    if (i < N) offs[i] = s[threadIdx.x] - v;
    if (threadIdx.x == 255) bsum[blockIdx.x] = s[255];
}

__global__ __launch_bounds__(256) void k_scanB(int* __restrict__ bsum, int nb) {
    __shared__ int s[256];
    int v = (threadIdx.x < nb) ? bsum[threadIdx.x] : 0;
    s[threadIdx.x] = v;
    __syncthreads();
    #pragma unroll
    for (int d = 1; d < 256; d <<= 1) {
        int t = (threadIdx.x >= d) ? s[threadIdx.x - d] : 0;
        __syncthreads();
        s[threadIdx.x] += t;
        __syncthreads();
    }
    if (threadIdx.x < nb) bsum[threadIdx.x] = s[threadIdx.x] - v;
}

__global__ __launch_bounds__(256) void k_scanC(int* __restrict__ offs, const int* __restrict__ bsum, int N) {
    int i = blockIdx.x * 256 + threadIdx.x;
    if (i < N) offs[i] += bsum[blockIdx.x];
}

// fills slotOf[e] and srcSl[slot] (src id stored in dst-sorted slot order)
__global__ __launch_bounds__(256) void k_fillD(const int* __restrict__ ei, const int* __restrict__ offs,
                                               int* __restrict__ cursor, int* __restrict__ slotOf,
                                               int* __restrict__ srcSl, int E) {
    int e = blockIdx.x * blockDim.x + threadIdx.x;
    if (e < E) {
        int d = ei[E + e];
        int slot = offs[d] + atomicAdd(&cursor[d], 1);
        slotOf[e] = slot;
        srcSl[slot] = ei[e];
    }
}

// ---------------- edge MLP a = relu(ea@w1+b1), stored in slot order (once) ----------------
__global__ __launch_bounds__(256) void k_a(
    const float* __restrict__ ea, const float* __restrict__ w1,
    const float* __restrict__ b1, const int* __restrict__ slotOf,
    float* __restrict__ aSl, int E)
{
    int e = blockIdx.x * 256 + threadIdx.x;
    if (e >= E) return;
    const float4* p = (const float4*)(ea + (size_t)e * 8);
    float4 v0 = p[0], v1 = p[1];
    float eav[8] = {v0.x, v0.y, v0.z, v0.w, v1.x, v1.y, v1.z, v1.w};
    float a[16];
    #pragma unroll
    for (int k = 0; k < 16; k++) a[k] = b1[k];
    #pragma unroll
    for (int q = 0; q < 8; q++) {
        float ev = eav[q];
        #pragma unroll
        for (int k = 0; k < 16; k++) a[k] += ev * w1[q * 16 + k];
    }
    int slot = slotOf[e];
    float4* o = (float4*)(aSl + (size_t)slot * 16);
    o[0] = make_float4(fmaxf(a[0],0.f), fmaxf(a[1],0.f), fmaxf(a[2],0.f), fmaxf(a[3],0.f));
    o[1] = make_float4(fmaxf(a[4],0.f), fmaxf(a[5],0.f), fmaxf(a[6],0.f), fmaxf(a[7],0.f));
    o[2] = make_float4(fmaxf(a[8],0.f), fmaxf(a[9],0.f), fmaxf(a[10],0.f), fmaxf(a[11],0.f));
    o[3] = make_float4(fmaxf(a[12],0.f), fmaxf(a[13],0.f), fmaxf(a[14],0.f), fmaxf(a[15],0.f));
}

// ---------------- fused conv layer ----------------
// thread (g,c): node n = blk*16+g, channel c. Edge loop builds B[k][c] in regs,
// LDS transpose, contract with w2/b2, + root + bias + relu + BN-stats.
// BN of the PREVIOUS layer is applied on the fly (scale/shift from statsPrev).
template<int BNPREV>
__global__ __launch_bounds__(256) void k_fuse(
    const float* __restrict__ hraw, const float* __restrict__ statsPrev,
    const float* __restrict__ gPrev, const float* __restrict__ bePrev,
    const int* __restrict__ offs, const int* __restrict__ cnt,
    const int* __restrict__ srcSl, const float* __restrict__ aSl,
    const float* __restrict__ w2, const float* __restrict__ b2,
    const float* __restrict__ root, const float* __restrict__ cb,
    float* __restrict__ hout, float* __restrict__ statsCur,
    int N, float invN)
{
    __shared__ float bm[16 * 340];   // [g][k(17) stride 20][c] ; reused for stats reduce
    __shared__ float scsh[32];
    int tid = threadIdx.x;
    if (BNPREV) {
        if (tid < 16) {
            float m = statsPrev[tid] * invN;
            float var = statsPrev[16 + tid] * invN - m * m;
            float sc = gPrev[tid] * rsqrtf(var + 1e-5f);
            scsh[tid] = sc;
            scsh[16 + tid] = bePrev[tid] - m * sc;
        }
        __syncthreads();
    }
    int g = tid >> 4, c = tid & 15;
    int n = blockIdx.x * 16 + g;
    float B[17];
    #pragma unroll
    for (int k = 0; k < 17; k++) B[k] = 0.f;
    float scC = 1.f, shC = 0.f;
    if (BNPREV) { scC = scsh[c]; shC = scsh[16 + c]; }
    if (n < N) {
        int start = offs[n], deg = cnt[n];
        for (int j = 0; j < deg; j++) {
            int slot = start + j;
            int src = srcSl[slot];
            float hs = hraw[(size_t)src * 16 + c] * scC + shC;
            const float4* ap = (const float4*)(aSl + (size_t)slot * 16);
            float4 a0 = ap[0], a1 = ap[1], a2 = ap[2], a3 = ap[3];
            B[0] += a0.x*hs; B[1] += a0.y*hs; B[2] += a0.z*hs; B[3] += a0.w*hs;
            B[4] += a1.x*hs; B[5] += a1.y*hs; B[6] += a1.z*hs; B[7] += a1.w*hs;
            B[8] += a2.x*hs; B[9] += a2.y*hs; B[10] += a2.z*hs; B[11] += a2.w*hs;
            B[12] += a3.x*hs; B[13] += a3.y*hs; B[14] += a3.z*hs; B[15] += a3.w*hs;
            B[16] += hs;
        }
    }
    float* bg = bm + g * 340;
    #pragma unroll
    for (int k = 0; k < 17; k++) bg[k * 20 + c] = B[k];
    __syncthreads();

    // contraction: this thread now produces output channel c of node n
    float part = 0.f;
    #pragma unroll
    for (int k = 0; k < 16; k++) {
        const float* wr = w2 + k * 256 + c;
        const float4* bp = (const float4*)(bg + k * 20);
        float4 b0 = bp[0], b1 = bp[1], b2v = bp[2], b3 = bp[3];
        part += b0.x*wr[0]   + b0.y*wr[16]  + b0.z*wr[32]  + b0.w*wr[48]
              + b1.x*wr[64]  + b1.y*wr[80]  + b1.z*wr[96]  + b1.w*wr[112]
              + b2v.x*wr[128]+ b2v.y*wr[144]+ b2v.z*wr[160]+ b2v.w*wr[176]
              + b3.x*wr[192] + b3.y*wr[208] + b3.z*wr[224] + b3.w*wr[240];
    }
    {
        const float* wr = b2 + c;
        const float4* bp = (const float4*)(bg + 16 * 20);
        float4 b0 = bp[0], b1 = bp[1], b2v = bp[2], b3 = bp[3];
        part += b0.x*wr[0]   + b0.y*wr[16]  + b0.z*wr[32]  + b0.w*wr[48]
              + b1.x*wr[64]  + b1.y*wr[80]  + b1.z*wr[96]  + b1.w*wr[112]
              + b2v.x*wr[128]+ b2v.y*wr[144]+ b2v.z*wr[160]+ b2v.w*wr[176]
              + b3.x*wr[192] + b3.y*wr[208] + b3.z*wr[224] + b3.w*wr[240];
    }

    float v = 0.f;
    if (n < N) {
        float hr[16];
        ld16(hraw + (size_t)n * 16, hr);
        v = cb[c] + part;
        #pragma unroll
        for (int j = 0; j < 16; j++) {
            float hv = hr[j];
            if (BNPREV) hv = hv * scsh[j] + scsh[16 + j];
            v += hv * root[j * 16 + c];
        }
        v = fmaxf(v, 0.f);
        hout[(size_t)n * 16 + c] = v;
    }
    __syncthreads();
    bm[tid] = v; bm[256 + tid] = v * v;
    __syncthreads();
    #pragma unroll
    for (int s = 128; s >= 16; s >>= 1) {
        if (tid < s) { bm[tid] += bm[tid + s]; bm[256 + tid] += bm[256 + tid + s]; }
        __syncthreads();
    }
    if (tid < 16) {
        atomicAdd(&statsCur[tid], bm[tid]);
        atomicAdd(&statsCur[16 + tid], bm[256 + tid]);
    }
}

// ---------------- mu / logvar / reparameterize (BN of layer 4 inlined) ----------------
__global__ __launch_bounds__(256) void k_z(
    const float* __restrict__ hraw, const float* __restrict__ stats4,
    const float* __restrict__ g4, const float* __restrict__ be4,
    const float* __restrict__ mu_w, const float* __restrict__ mu_b,
    const float* __restrict__ lv_w, const float* __restrict__ lv_b,
    const float* __restrict__ eps, float* __restrict__ z, int N, float invN)
{
    __shared__ float scsh[32];
    int tid = threadIdx.x;
    if (tid < 16) {
        float m = stats4[tid] * invN;
        float var = stats4[16 + tid] * invN - m * m;
        float sc = g4[tid] * rsqrtf(var + 1e-5f);
        scsh[tid] = sc;
        scsh[16 + tid] = be4[tid] - m * sc;
    }
    __syncthreads();
    int t = blockIdx.x * 256 + tid;
    if (t >= N * 16) return;
    int n = t >> 4, o = t & 15;
    float hr[16];
    ld16(hraw + (size_t)n * 16, hr);
    float mu = mu_b[o], lv = lv_b[o];
    #pragma unroll
    for (int j = 0; j < 16; j++) {
        float hv = hr[j] * scsh[j] + scsh[16 + j];
        mu += hv * mu_w[j * 16 + o];
        lv += hv * lv_w[j * 16 + o];
    }
    lv = fminf(lv, 10.f);
    z[t] = mu + eps[t] * expf(0.5f * lv);
}

// ---------------- decoder: 4-way o-split, register accumulators ----------------
__device__ __forceinline__ void dec64q(const float* __restrict__ wmat,
                                       const float* __restrict__ bias,
                                       float* row, int Wof, float* acc)
{
    #pragma unroll
    for (int o = 0; o < 16; o++) acc[o] = bias[Wof + o];
    #pragma unroll 4
    for (int i = 0; i < 64; i++) {
        float ai = row[i];
        const float4* w = (const float4*)(wmat + i * 64 + Wof);
        #pragma unroll
        for (int q = 0; q < 4; q++) {
            float4 wv = w[q];
            acc[q*4+0] += ai * wv.x; acc[q*4+1] += ai * wv.y;
            acc[q*4+2] += ai * wv.z; acc[q*4+3] += ai * wv.w;
        }
    }
    __syncthreads();
    #pragma unroll
    for (int o = 0; o < 16; o++) row[Wof + o] = fmaxf(acc[o], 0.f);
    __syncthreads();
}

__global__ __launch_bounds__(256) void k_dec(
    const float* __restrict__ z, const int* __restrict__ ei,
    const float* __restrict__ dw0, const float* __restrict__ db0,
    const float* __restrict__ dw1, const float* __restrict__ db1,
    const float* __restrict__ dw2, const float* __restrict__ db2,
    const float* __restrict__ dw3, const float* __restrict__ db3,
    const float* __restrict__ dw4, const float* __restrict__ db4,
    float* __restrict__ out, int E)
{
    __shared__ float act[64 * 65];
    int tid = threadIdx.x;
    int l = tid & 63;
    int W = tid >> 6;              // 0..3
    int e = blockIdx.x * 64 + l;
    float* row = act + l * 65;

    if (e < E && W < 2) {
        int nd = (W == 0) ? ei[e] : ei[E + e];
        const float4* zp = (const float4*)(z + (size_t)nd * 16);
        #pragma unroll
        for (int q = 0; q < 4; q++) {
            float4 v = zp[q];
            row[W * 16 + q * 4 + 0] = v.x;
            row[W * 16 + q * 4 + 1] = v.y;
            row[W * 16 + q * 4 + 2] = v.z;
            row[W * 16 + q * 4 + 3] = v.w;
        }
    }
    __syncthreads();

    float acc[16];
    int Wof = W * 16;

    // layer 0: 32 -> 64
    #pragma unroll
    for (int o = 0; o < 16; o++) acc[o] = db0[Wof + o];
    #pragma unroll 4
    for (int i = 0; i < 32; i++) {
        float ai = row[i];
        const float4* w = (const float4*)(dw0 + i * 64 + Wof);
        #pragma unroll
        for (int q = 0; q < 4; q++) {
            float4 wv = w[q];
            acc[q*4+0] += ai * wv.x; acc[q*4+1] += ai * wv.y;
            acc[q*4+2] += ai * wv.z; acc[q*4+3] += ai * wv.w;
        }
    }
    __syncthreads();
    #pragma unroll
    for (int o = 0; o < 16; o++) row[Wof + o] = fmaxf(acc[o], 0.f);
    __syncthreads();

    dec64q(dw1, db1, row, Wof, acc);
    dec64q(dw2, db2, row, Wof, acc);
    dec64q(dw3, db3, row, Wof, acc);

    // final: 64 -> 8 ; wave W computes outputs [W*2, W*2+2)
    float r0 = db4[W * 2], r1 = db4[W * 2 + 1];
    #pragma unroll 4
    for (int i = 0; i < 64; i++) {
        float ai = row[i];
        float2 wv = *(const float2*)(dw4 + i * 8 + W * 2);
        r0 += ai * wv.x; r1 += ai * wv.y;
    }
    if (e < E) {
        *(float2*)(out + (size_t)e * 8 + W * 2) = make_float2(r0, r1);
    }
}

// ---------------- launch ----------------
extern "C" void kernel_launch(void* const* d_in, const int* in_sizes, int n_in,
                              void* d_out, int out_size, void* d_ws, size_t ws_size,
                              hipStream_t stream)
{
    const float* x   = (const float*)d_in[0];
    const int*   ei  = (const int*)d_in[1];
    const float* ea  = (const float*)d_in[2];
    const float* eps = (const float*)d_in[3];
    const float* w1  = (const float*)d_in[4];
    const float* b1  = (const float*)d_in[5];
    const float* w2  = (const float*)d_in[6];
    const float* b2  = (const float*)d_in[7];
    const float* root[4]; const float* cb[4]; const float* g[4]; const float* be[4];
    for (int l = 0; l < 4; l++) {
        root[l] = (const float*)d_in[8 + 4*l];
        cb[l]   = (const float*)d_in[9 + 4*l];
        g[l]    = (const float*)d_in[10 + 4*l];
        be[l]   = (const float*)d_in[11 + 4*l];
    }
    const float* mu_w = (const float*)d_in[24];
    const float* mu_b = (const float*)d_in[25];
    const float* lv_w = (const float*)d_in[26];
    const float* lv_b = (const float*)d_in[27];
    const float* dw[5]; const float* db[5];
    for (int i = 0; i < 5; i++) {
        dw[i] = (const float*)d_in[28 + 2*i];
        db[i] = (const float*)d_in[29 + 2*i];
    }
    float* out = (float*)d_out;

    int N = in_sizes[0] / 16;
    int E = in_sizes[2] / 8;
    float invN = 1.0f / N;

    // ---- workspace layout ----
    int*   cnt      = (int*)d_ws;                 // N
    int*   cursor   = cnt + N;                    // N
    float* statsAll = (float*)(cursor + N);       // 128 (4 layers x 32)
    int*   offs     = (int*)(statsAll + 128);     // N
    int*   bsum     = offs + N;                   // 256
    int*   slotOf   = bsum + 256;                 // E
    int*   srcSl    = slotOf + E;                 // E
    float* aSl      = (float*)(srcSl + E);        // E*16
    float* hA       = aSl + (size_t)E * 16;       // N*16
    float* hB       = hA + (size_t)N * 16;        // N*16
    float* zbuf     = hB + (size_t)N * 16;        // N*16

    int nbScan = (N + 255) / 256;                 // <=256 blocks

    // zero cnt + cursor + statsAll in one memset
    hipMemsetAsync(cnt, 0, ((size_t)2 * N + 128) * sizeof(int), stream);

    // ---- dst-CSR ----
    k_count<<<(E + 255) / 256, 256, 0, stream>>>(ei, cnt, E);
    k_scanA<<<nbScan, 256, 0, stream>>>(cnt, offs, bsum, N);
    k_scanB<<<1, 256, 0, stream>>>(bsum, nbScan);
    k_scanC<<<nbScan, 256, 0, stream>>>(offs, bsum, N);
    k_fillD<<<(E + 255) / 256, 256, 0, stream>>>(ei, offs, cursor, slotOf, srcSl, E);

    // ---- edge MLP once (layer-independent) ----
    k_a<<<(E + 255) / 256, 256, 0, stream>>>(ea, w1, b1, slotOf, aSl, E);

    int nbF = (N + 15) / 16;
    // ---- 4 fused conv layers (BN of prev layer applied inline) ----
    k_fuse<0><<<nbF, 256, 0, stream>>>(x,  nullptr,      nullptr, nullptr,
                                       offs, cnt, srcSl, aSl, w2, b2,
                                       root[0], cb[0], hA, statsAll + 0,  N, invN);
    k_fuse<1><<<nbF, 256, 0, stream>>>(hA, statsAll + 0,  g[0], be[0],
                                       offs, cnt, srcSl, aSl, w2, b2,
                                       root[1], cb[1], hB, statsAll + 32, N, invN);
    k_fuse<1><<<nbF, 256, 0, stream>>>(hB, statsAll + 32, g[1], be[1],
                                       offs, cnt, srcSl, aSl, w2, b2,
                                       root[2], cb[2], hA, statsAll + 64, N, invN);
    k_fuse<1><<<nbF, 256, 0, stream>>>(hA, statsAll + 64, g[2], be[2],
                                       offs, cnt, srcSl, aSl, w2, b2,
                                       root[3], cb[3], hB, statsAll + 96, N, invN);

    k_z<<<(N * 16 + 255) / 256, 256, 0, stream>>>(hB, statsAll + 96, g[3], be[3],
                                                  mu_w, mu_b, lv_w, lv_b, eps, zbuf, N, invN);
    k_dec<<<(E + 63) / 64, 256, 0, stream>>>(zbuf, ei,
        dw[0], db[0], dw[1], db[1], dw[2], db[2], dw[3], db[3], dw[4], db[4], out, E);
}

// Round 5
// 715.707 us; speedup vs baseline: 2.4712x; 2.4712x over previous
//
#include <hip/hip_runtime.h>
#include <math.h>

// ---------------- helpers ----------------
__device__ __forceinline__ void ld16(const float* __restrict__ p, float* a) {
    const float4* q = (const float4*)p;
    float4 v0 = q[0], v1 = q[1], v2 = q[2], v3 = q[3];
    a[0]=v0.x; a[1]=v0.y; a[2]=v0.z; a[3]=v0.w;
    a[4]=v1.x; a[5]=v1.y; a[6]=v1.z; a[7]=v1.w;
    a[8]=v2.x; a[9]=v2.y; a[10]=v2.z; a[11]=v2.w;
    a[12]=v3.x; a[13]=v3.y; a[14]=v3.z; a[15]=v3.w;
}

// ---------------- CSR build ----------------
__global__ __launch_bounds__(256) void k_count(const int* __restrict__ ei, int* __restrict__ cnt, int E) {
    int e = blockIdx.x * blockDim.x + threadIdx.x;
    if (e < E) atomicAdd(&cnt[ei[E + e]], 1);
}

__global__ __launch_bounds__(256) void k_scanA(const int* __restrict__ cnt, int* __restrict__ offs,
                                               int* __restrict__ bsum, int N) {
    __shared__ int s[256];
    int i = blockIdx.x * 256 + threadIdx.x;
    int v = (i < N) ? cnt[i] : 0;
    s[threadIdx.x] = v;
    __syncthreads();
    #pragma unroll
    for (int d = 1; d < 256; d <<= 1) {
        int t = (threadIdx.x >= d) ? s[threadIdx.x - d] : 0;
        __syncthreads();
        s[threadIdx.x] += t;
        __syncthreads();
    }
    if (i < N) offs[i] = s[threadIdx.x] - v;
    if (threadIdx.x == 255) bsum[blockIdx.x] = s[255];
}

__global__ __launch_bounds__(256) void k_scanB(int* __restrict__ bsum, int nb) {
    __shared__ int s[256];
    int v = (threadIdx.x < nb) ? bsum[threadIdx.x] : 0;
    s[threadIdx.x] = v;
    __syncthreads();
    #pragma unroll
    for (int d = 1; d < 256; d <<= 1) {
        int t = (threadIdx.x >= d) ? s[threadIdx.x - d] : 0;
        __syncthreads();
        s[threadIdx.x] += t;
        __syncthreads();
    }
    if (threadIdx.x < nb) bsum[threadIdx.x] = s[threadIdx.x] - v;
}

__global__ __launch_bounds__(256) void k_scanC(int* __restrict__ offs, const int* __restrict__ bsum, int N) {
    int i = blockIdx.x * 256 + threadIdx.x;
    if (i < N) offs[i] += bsum[blockIdx.x];
}

// fills slotOf[e] and srcSl[slot] (src id stored in dst-sorted slot order)
__global__ __launch_bounds__(256) void k_fillD(const int* __restrict__ ei, const int* __restrict__ offs,
                                               int* __restrict__ cursor, int* __restrict__ slotOf,
                                               int* __restrict__ srcSl, int E) {
    int e = blockIdx.x * blockDim.x + threadIdx.x;
    if (e < E) {
        int d = ei[E + e];
        int slot = offs[d] + atomicAdd(&cursor[d], 1);
        slotOf[e] = slot;
        srcSl[slot] = ei[e];
    }
}

// ---------------- edge MLP a = relu(ea@w1+b1), stored in slot order (once) ----------------
__global__ __launch_bounds__(256) void k_a(
    const float* __restrict__ ea, const float* __restrict__ w1,
    const float* __restrict__ b1, const int* __restrict__ slotOf,
    float* __restrict__ aSl, int E)
{
    int e = blockIdx.x * 256 + threadIdx.x;
    if (e >= E) return;
    const float4* p = (const float4*)(ea + (size_t)e * 8);
    float4 v0 = p[0], v1 = p[1];
    float eav[8] = {v0.x, v0.y, v0.z, v0.w, v1.x, v1.y, v1.z, v1.w};
    float a[16];
    #pragma unroll
    for (int k = 0; k < 16; k++) a[k] = b1[k];
    #pragma unroll
    for (int q = 0; q < 8; q++) {
        float ev = eav[q];
        #pragma unroll
        for (int k = 0; k < 16; k++) a[k] += ev * w1[q * 16 + k];
    }
    int slot = slotOf[e];
    float4* o = (float4*)(aSl + (size_t)slot * 16);
    o[0] = make_float4(fmaxf(a[0],0.f), fmaxf(a[1],0.f), fmaxf(a[2],0.f), fmaxf(a[3],0.f));
    o[1] = make_float4(fmaxf(a[4],0.f), fmaxf(a[5],0.f), fmaxf(a[6],0.f), fmaxf(a[7],0.f));
    o[2] = make_float4(fmaxf(a[8],0.f), fmaxf(a[9],0.f), fmaxf(a[10],0.f), fmaxf(a[11],0.f));
    o[3] = make_float4(fmaxf(a[12],0.f), fmaxf(a[13],0.f), fmaxf(a[14],0.f), fmaxf(a[15],0.f));
}

// ---------------- fused conv layer ----------------
// thread (g,c): node n = blk*16+g, channel c. Edge loop builds B[k][c] in regs,
// LDS transpose, contract with w2/b2, + root + bias + relu + BN-stats.
// BN of the PREVIOUS layer is applied on the fly (scale/shift from statsPrev).
template<int BNPREV>
__global__ __launch_bounds__(256) void k_fuse(
    const float* __restrict__ hraw, const float* __restrict__ statsPrev,
    const float* __restrict__ gPrev, const float* __restrict__ bePrev,
    const int* __restrict__ offs, const int* __restrict__ cnt,
    const int* __restrict__ srcSl, const float* __restrict__ aSl,
    const float* __restrict__ w2, const float* __restrict__ b2,
    const float* __restrict__ root, const float* __restrict__ cb,
    float* __restrict__ hout, float* __restrict__ statsCur,
    int N, float invN)
{
    __shared__ float bm[16 * 340];   // [g][k(17) stride 20][c] ; reused for stats reduce
    __shared__ float scsh[32];
    int tid = threadIdx.x;
    if (BNPREV) {
        if (tid < 16) {
            float m = statsPrev[tid] * invN;
            float var = statsPrev[16 + tid] * invN - m * m;
            float sc = gPrev[tid] * rsqrtf(var + 1e-5f);
            scsh[tid] = sc;
            scsh[16 + tid] = bePrev[tid] - m * sc;
        }
        __syncthreads();
    }
    int g = tid >> 4, c = tid & 15;
    int n = blockIdx.x * 16 + g;
    float B[17];
    #pragma unroll
    for (int k = 0; k < 17; k++) B[k] = 0.f;
    float scC = 1.f, shC = 0.f;
    if (BNPREV) { scC = scsh[c]; shC = scsh[16 + c]; }
    if (n < N) {
        int start = offs[n], deg = cnt[n];
        for (int j = 0; j < deg; j++) {
            int slot = start + j;
            int src = srcSl[slot];
            float hs = hraw[(size_t)src * 16 + c] * scC + shC;
            const float4* ap = (const float4*)(aSl + (size_t)slot * 16);
            float4 a0 = ap[0], a1 = ap[1], a2 = ap[2], a3 = ap[3];
            B[0] += a0.x*hs; B[1] += a0.y*hs; B[2] += a0.z*hs; B[3] += a0.w*hs;
            B[4] += a1.x*hs; B[5] += a1.y*hs; B[6] += a1.z*hs; B[7] += a1.w*hs;
            B[8] += a2.x*hs; B[9] += a2.y*hs; B[10] += a2.z*hs; B[11] += a2.w*hs;
            B[12] += a3.x*hs; B[13] += a3.y*hs; B[14] += a3.z*hs; B[15] += a3.w*hs;
            B[16] += hs;
        }
    }
    float* bg = bm + g * 340;
    #pragma unroll
    for (int k = 0; k < 17; k++) bg[k * 20 + c] = B[k];
    __syncthreads();

    // contraction: this thread now produces output channel c of node n
    float part = 0.f;
    #pragma unroll
    for (int k = 0; k < 16; k++) {
        const float* wr = w2 + k * 256 + c;
        const float4* bp = (const float4*)(bg + k * 20);
        float4 b0 = bp[0], b1 = bp[1], b2v = bp[2], b3 = bp[3];
        part += b0.x*wr[0]   + b0.y*wr[16]  + b0.z*wr[32]  + b0.w*wr[48]
              + b1.x*wr[64]  + b1.y*wr[80]  + b1.z*wr[96]  + b1.w*wr[112]
              + b2v.x*wr[128]+ b2v.y*wr[144]+ b2v.z*wr[160]+ b2v.w*wr[176]
              + b3.x*wr[192] + b3.y*wr[208] + b3.z*wr[224] + b3.w*wr[240];
    }
    {
        const float* wr = b2 + c;
        const float4* bp = (const float4*)(bg + 16 * 20);
        float4 b0 = bp[0], b1 = bp[1], b2v = bp[2], b3 = bp[3];
        part += b0.x*wr[0]   + b0.y*wr[16]  + b0.z*wr[32]  + b0.w*wr[48]
              + b1.x*wr[64]  + b1.y*wr[80]  + b1.z*wr[96]  + b1.w*wr[112]
              + b2v.x*wr[128]+ b2v.y*wr[144]+ b2v.z*wr[160]+ b2v.w*wr[176]
              + b3.x*wr[192] + b3.y*wr[208] + b3.z*wr[224] + b3.w*wr[240];
    }

    float v = 0.f;
    if (n < N) {
        float hr[16];
        ld16(hraw + (size_t)n * 16, hr);
        v = cb[c] + part;
        #pragma unroll
        for (int j = 0; j < 16; j++) {
            float hv = hr[j];
            if (BNPREV) hv = hv * scsh[j] + scsh[16 + j];
            v += hv * root[j * 16 + c];
        }
        v = fmaxf(v, 0.f);
        hout[(size_t)n * 16 + c] = v;
    }
    __syncthreads();
    bm[tid] = v; bm[256 + tid] = v * v;
    __syncthreads();
    #pragma unroll
    for (int s = 128; s >= 16; s >>= 1) {
        if (tid < s) { bm[tid] += bm[tid + s]; bm[256 + tid] += bm[256 + tid + s]; }
        __syncthreads();
    }
    if (tid < 16) {
        atomicAdd(&statsCur[tid], bm[tid]);
        atomicAdd(&statsCur[16 + tid], bm[256 + tid]);
    }
}

// ---------------- mu / logvar / reparameterize (BN of layer 4 inlined) ----------------
__global__ __launch_bounds__(256) void k_z(
    const float* __restrict__ hraw, const float* __restrict__ stats4,
    const float* __restrict__ g4, const float* __restrict__ be4,
    const float* __restrict__ mu_w, const float* __restrict__ mu_b,
    const float* __restrict__ lv_w, const float* __restrict__ lv_b,
    const float* __restrict__ eps, float* __restrict__ z, int N, float invN)
{
    __shared__ float scsh[32];
    int tid = threadIdx.x;
    if (tid < 16) {
        float m = stats4[tid] * invN;
        float var = stats4[16 + tid] * invN - m * m;
        float sc = g4[tid] * rsqrtf(var + 1e-5f);
        scsh[tid] = sc;
        scsh[16 + tid] = be4[tid] - m * sc;
    }
    __syncthreads();
    int t = blockIdx.x * 256 + tid;
    if (t >= N * 16) return;
    int n = t >> 4, o = t & 15;
    float hr[16];
    ld16(hraw + (size_t)n * 16, hr);
    float mu = mu_b[o], lv = lv_b[o];
    #pragma unroll
    for (int j = 0; j < 16; j++) {
        float hv = hr[j] * scsh[j] + scsh[16 + j];
        mu += hv * mu_w[j * 16 + o];
        lv += hv * lv_w[j * 16 + o];
    }
    lv = fminf(lv, 10.f);
    z[t] = mu + eps[t] * expf(0.5f * lv);
}

// ---------------- decoder: register accumulators, wave-split outputs ----------------
// W derived via readfirstlane => weight addresses are provably wave-uniform =>
// compiler emits scalar s_load for weights (SGPR~112). DO NOT remove it:
// R4 (plain tid>>6) regressed 313->1418us from per-lane VMEM weight loads.
__device__ __forceinline__ void dec64(const float* __restrict__ wmat,
                                      const float* __restrict__ bias,
                                      float* row, int Wof, float* acc)
{
    #pragma unroll
    for (int o = 0; o < 32; o++) acc[o] = bias[Wof + o];
    #pragma unroll 2
    for (int i = 0; i < 64; i++) {
        float ai = row[i];
        const float4* w = (const float4*)(wmat + i * 64 + Wof);
        #pragma unroll
        for (int q = 0; q < 8; q++) {
            float4 wv = w[q];
            acc[q*4+0] += ai * wv.x; acc[q*4+1] += ai * wv.y;
            acc[q*4+2] += ai * wv.z; acc[q*4+3] += ai * wv.w;
        }
    }
    __syncthreads();
    #pragma unroll
    for (int o = 0; o < 32; o++) row[Wof + o] = fmaxf(acc[o], 0.f);
    __syncthreads();
}

__global__ __launch_bounds__(128) void k_dec(
    const float* __restrict__ z, const int* __restrict__ ei,
    const float* __restrict__ dw0, const float* __restrict__ db0,
    const float* __restrict__ dw1, const float* __restrict__ db1,
    const float* __restrict__ dw2, const float* __restrict__ db2,
    const float* __restrict__ dw3, const float* __restrict__ db3,
    const float* __restrict__ dw4, const float* __restrict__ db4,
    float* __restrict__ out, int E)
{
    __shared__ float act[64 * 65];
    int l = threadIdx.x & 63;
    int W = __builtin_amdgcn_readfirstlane(threadIdx.x >> 6);
    int e = blockIdx.x * 64 + l;
    float* row = act + l * 65;

    // stage inputs: wave0 -> z[src] into [0..15], wave1 -> z[dst] into [16..31]
    if (e < E) {
        int nd = (W == 0) ? ei[e] : ei[E + e];
        const float4* zp = (const float4*)(z + (size_t)nd * 16);
        #pragma unroll
        for (int q = 0; q < 4; q++) {
            float4 v = zp[q];
            row[W * 16 + q * 4 + 0] = v.x;
            row[W * 16 + q * 4 + 1] = v.y;
            row[W * 16 + q * 4 + 2] = v.z;
            row[W * 16 + q * 4 + 3] = v.w;
        }
    }
    __syncthreads();

    float acc[32];
    int Wof = W * 32;

    // layer 0: 32 -> 64
    #pragma unroll
    for (int o = 0; o < 32; o++) acc[o] = db0[Wof + o];
    #pragma unroll 2
    for (int i = 0; i < 32; i++) {
        float ai = row[i];
        const float4* w = (const float4*)(dw0 + i * 64 + Wof);
        #pragma unroll
        for (int q = 0; q < 8; q++) {
            float4 wv = w[q];
            acc[q*4+0] += ai * wv.x; acc[q*4+1] += ai * wv.y;
            acc[q*4+2] += ai * wv.z; acc[q*4+3] += ai * wv.w;
        }
    }
    __syncthreads();
    #pragma unroll
    for (int o = 0; o < 32; o++) row[Wof + o] = fmaxf(acc[o], 0.f);
    __syncthreads();

    dec64(dw1, db1, row, Wof, acc);
    dec64(dw2, db2, row, Wof, acc);
    dec64(dw3, db3, row, Wof, acc);

    // final: 64 -> 8 ; wave W computes outputs [W*4, W*4+4)
    float r[4];
    #pragma unroll
    for (int j = 0; j < 4; j++) r[j] = db4[W * 4 + j];
    #pragma unroll 2
    for (int i = 0; i < 64; i++) {
        float ai = row[i];
        float4 wv = *(const float4*)(dw4 + i * 8 + W * 4);
        r[0] += ai * wv.x; r[1] += ai * wv.y; r[2] += ai * wv.z; r[3] += ai * wv.w;
    }
    if (e < E) {
        *(float4*)(out + (size_t)e * 8 + W * 4) = make_float4(r[0], r[1], r[2], r[3]);
    }
}

// ---------------- launch ----------------
extern "C" void kernel_launch(void* const* d_in, const int* in_sizes, int n_in,
                              void* d_out, int out_size, void* d_ws, size_t ws_size,
                              hipStream_t stream)
{
    const float* x   = (const float*)d_in[0];
    const int*   ei  = (const int*)d_in[1];
    const float* ea  = (const float*)d_in[2];
    const float* eps = (const float*)d_in[3];
    const float* w1  = (const float*)d_in[4];
    const float* b1  = (const float*)d_in[5];
    const float* w2  = (const float*)d_in[6];
    const float* b2  = (const float*)d_in[7];
    const float* root[4]; const float* cb[4]; const float* g[4]; const float* be[4];
    for (int l = 0; l < 4; l++) {
        root[l] = (const float*)d_in[8 + 4*l];
        cb[l]   = (const float*)d_in[9 + 4*l];
        g[l]    = (const float*)d_in[10 + 4*l];
        be[l]   = (const float*)d_in[11 + 4*l];
    }
    const float* mu_w = (const float*)d_in[24];
    const float* mu_b = (const float*)d_in[25];
    const float* lv_w = (const float*)d_in[26];
    const float* lv_b = (const float*)d_in[27];
    const float* dw[5]; const float* db[5];
    for (int i = 0; i < 5; i++) {
        dw[i] = (const float*)d_in[28 + 2*i];
        db[i] = (const float*)d_in[29 + 2*i];
    }
    float* out = (float*)d_out;

    int N = in_sizes[0] / 16;
    int E = in_sizes[2] / 8;
    float invN = 1.0f / N;

    // ---- workspace layout ----
    int*   cnt      = (int*)d_ws;                 // N
    int*   cursor   = cnt + N;                    // N
    float* statsAll = (float*)(cursor + N);       // 128 (4 layers x 32)
    int*   offs     = (int*)(statsAll + 128);     // N
    int*   bsum     = offs + N;                   // 256
    int*   slotOf   = bsum + 256;                 // E
    int*   srcSl    = slotOf + E;                 // E
    float* aSl      = (float*)(srcSl + E);        // E*16
    float* hA       = aSl + (size_t)E * 16;       // N*16
    float* hB       = hA + (size_t)N * 16;        // N*16
    float* zbuf     = hB + (size_t)N * 16;        // N*16

    int nbScan = (N + 255) / 256;                 // <=256 blocks

    // zero cnt + cursor + statsAll in one memset
    hipMemsetAsync(cnt, 0, ((size_t)2 * N + 128) * sizeof(int), stream);

    // ---- dst-CSR ----
    k_count<<<(E + 255) / 256, 256, 0, stream>>>(ei, cnt, E);
    k_scanA<<<nbScan, 256, 0, stream>>>(cnt, offs, bsum, N);
    k_scanB<<<1, 256, 0, stream>>>(bsum, nbScan);
    k_scanC<<<nbScan, 256, 0, stream>>>(offs, bsum, N);
    k_fillD<<<(E + 255) / 256, 256, 0, stream>>>(ei, offs, cursor, slotOf, srcSl, E);

    // ---- edge MLP once (layer-independent) ----
    k_a<<<(E + 255) / 256, 256, 0, stream>>>(ea, w1, b1, slotOf, aSl, E);

    int nbF = (N + 15) / 16;
    // ---- 4 fused conv layers (BN of prev layer applied inline) ----
    k_fuse<0><<<nbF, 256, 0, stream>>>(x,  nullptr,      nullptr, nullptr,
                                       offs, cnt, srcSl, aSl, w2, b2,
                                       root[0], cb[0], hA, statsAll + 0,  N, invN);
    k_fuse<1><<<nbF, 256, 0, stream>>>(hA, statsAll + 0,  g[0], be[0],
                                       offs, cnt, srcSl, aSl, w2, b2,
                                       root[1], cb[1], hB, statsAll + 32, N, invN);
    k_fuse<1><<<nbF, 256, 0, stream>>>(hB, statsAll + 32, g[1], be[1],
                                       offs, cnt, srcSl, aSl, w2, b2,
                                       root[2], cb[2], hA, statsAll + 64, N, invN);
    k_fuse<1><<<nbF, 256, 0, stream>>>(hA, statsAll + 64, g[2], be[2],
                                       offs, cnt, srcSl, aSl, w2, b2,
                                       root[3], cb[3], hB, statsAll + 96, N, invN);

    k_z<<<(N * 16 + 255) / 256, 256, 0, stream>>>(hB, statsAll + 96, g[3], be[3],
                                                  mu_w, mu_b, lv_w, lv_b, eps, zbuf, N, invN);
    k_dec<<<(E + 63) / 64, 128, 0, stream>>>(zbuf, ei,
        dw[0], db[0], dw[1], db[1], dw[2], db[2], dw[3], db[3], dw[4], db[4], out, E);
}

// Round 6
// 504.897 us; speedup vs baseline: 3.5029x; 1.4175x over previous
//
#include <hip/hip_runtime.h>
#include <hip/hip_bf16.h>
#include <math.h>

using short8 = __attribute__((ext_vector_type(8))) short;
using f32x4  = __attribute__((ext_vector_type(4))) float;

__device__ __forceinline__ unsigned short f2bf(float x) {
    return __builtin_bit_cast(unsigned short, __float2bfloat16(x));
}

#define MFMA16(A,B,C) __builtin_amdgcn_mfma_f32_16x16x32_bf16((A),(B),(C),0,0,0)

// ---------------- helpers ----------------
__device__ __forceinline__ void ld16(const float* __restrict__ p, float* a) {
    const float4* q = (const float4*)p;
    float4 v0 = q[0], v1 = q[1], v2 = q[2], v3 = q[3];
    a[0]=v0.x; a[1]=v0.y; a[2]=v0.z; a[3]=v0.w;
    a[4]=v1.x; a[5]=v1.y; a[6]=v1.z; a[7]=v1.w;
    a[8]=v2.x; a[9]=v2.y; a[10]=v2.z; a[11]=v2.w;
    a[12]=v3.x; a[13]=v3.y; a[14]=v3.z; a[15]=v3.w;
}

// ---------------- CSR build ----------------
__global__ __launch_bounds__(256) void k_count(const int* __restrict__ ei, int* __restrict__ cnt, int E) {
    int e = blockIdx.x * blockDim.x + threadIdx.x;
    if (e < E) atomicAdd(&cnt[ei[E + e]], 1);
}

__global__ __launch_bounds__(256) void k_scanA(const int* __restrict__ cnt, int* __restrict__ offs,
                                               int* __restrict__ bsum, int N) {
    __shared__ int s[256];
    int i = blockIdx.x * 256 + threadIdx.x;
    int v = (i < N) ? cnt[i] : 0;
    s[threadIdx.x] = v;
    __syncthreads();
    #pragma unroll
    for (int d = 1; d < 256; d <<= 1) {
        int t = (threadIdx.x >= d) ? s[threadIdx.x - d] : 0;
        __syncthreads();
        s[threadIdx.x] += t;
        __syncthreads();
    }
    if (i < N) offs[i] = s[threadIdx.x] - v;
    if (threadIdx.x == 255) bsum[blockIdx.x] = s[255];
}

__global__ __launch_bounds__(256) void k_scanB(int* __restrict__ bsum, int nb) {
    __shared__ int s[256];
    int v = (threadIdx.x < nb) ? bsum[threadIdx.x] : 0;
    s[threadIdx.x] = v;
    __syncthreads();
    #pragma unroll
    for (int d = 1; d < 256; d <<= 1) {
        int t = (threadIdx.x >= d) ? s[threadIdx.x - d] : 0;
        __syncthreads();
        s[threadIdx.x] += t;
        __syncthreads();
    }
    if (threadIdx.x < nb) bsum[threadIdx.x] = s[threadIdx.x] - v;
}

__global__ __launch_bounds__(256) void k_scanC(int* __restrict__ offs, const int* __restrict__ bsum, int N) {
    int i = blockIdx.x * 256 + threadIdx.x;
    if (i < N) offs[i] += bsum[blockIdx.x];
}

__global__ __launch_bounds__(256) void k_fillD(const int* __restrict__ ei, const int* __restrict__ offs,
                                               int* __restrict__ cursor, int* __restrict__ slotOf,
                                               int* __restrict__ srcSl, int E) {
    int e = blockIdx.x * blockDim.x + threadIdx.x;
    if (e < E) {
        int d = ei[E + e];
        int slot = offs[d] + atomicAdd(&cursor[d], 1);
        slotOf[e] = slot;
        srcSl[slot] = ei[e];
    }
}

// ---------------- edge MLP a = relu(ea@w1+b1), stored in slot order (once) ----------------
__global__ __launch_bounds__(256) void k_a(
    const float* __restrict__ ea, const float* __restrict__ w1,
    const float* __restrict__ b1, const int* __restrict__ slotOf,
    float* __restrict__ aSl, int E)
{
    int e = blockIdx.x * 256 + threadIdx.x;
    if (e >= E) return;
    const float4* p = (const float4*)(ea + (size_t)e * 8);
    float4 v0 = p[0], v1 = p[1];
    float eav[8] = {v0.x, v0.y, v0.z, v0.w, v1.x, v1.y, v1.z, v1.w};
    float a[16];
    #pragma unroll
    for (int k = 0; k < 16; k++) a[k] = b1[k];
    #pragma unroll
    for (int q = 0; q < 8; q++) {
        float ev = eav[q];
        #pragma unroll
        for (int k = 0; k < 16; k++) a[k] += ev * w1[q * 16 + k];
    }
    int slot = slotOf[e];
    float4* o = (float4*)(aSl + (size_t)slot * 16);
    o[0] = make_float4(fmaxf(a[0],0.f), fmaxf(a[1],0.f), fmaxf(a[2],0.f), fmaxf(a[3],0.f));
    o[1] = make_float4(fmaxf(a[4],0.f), fmaxf(a[5],0.f), fmaxf(a[6],0.f), fmaxf(a[7],0.f));
    o[2] = make_float4(fmaxf(a[8],0.f), fmaxf(a[9],0.f), fmaxf(a[10],0.f), fmaxf(a[11],0.f));
    o[3] = make_float4(fmaxf(a[12],0.f), fmaxf(a[13],0.f), fmaxf(a[14],0.f), fmaxf(a[15],0.f));
}

// ---------------- fused conv layer ----------------
template<int BNPREV>
__global__ __launch_bounds__(256) void k_fuse(
    const float* __restrict__ hraw, const float* __restrict__ statsPrev,
    const float* __restrict__ gPrev, const float* __restrict__ bePrev,
    const int* __restrict__ offs, const int* __restrict__ cnt,
    const int* __restrict__ srcSl, const float* __restrict__ aSl,
    const float* __restrict__ w2, const float* __restrict__ b2,
    const float* __restrict__ root, const float* __restrict__ cb,
    float* __restrict__ hout, float* __restrict__ statsCur,
    int N, float invN)
{
    __shared__ float bm[16 * 340];   // [g][k(17) stride 20][c] ; reused for stats reduce
    __shared__ float scsh[32];
    int tid = threadIdx.x;
    if (BNPREV) {
        if (tid < 16) {
            float m = statsPrev[tid] * invN;
            float var = statsPrev[16 + tid] * invN - m * m;
            float sc = gPrev[tid] * rsqrtf(var + 1e-5f);
            scsh[tid] = sc;
            scsh[16 + tid] = bePrev[tid] - m * sc;
        }
        __syncthreads();
    }
    int g = tid >> 4, c = tid & 15;
    int n = blockIdx.x * 16 + g;
    float B[17];
    #pragma unroll
    for (int k = 0; k < 17; k++) B[k] = 0.f;
    float scC = 1.f, shC = 0.f;
    if (BNPREV) { scC = scsh[c]; shC = scsh[16 + c]; }
    if (n < N) {
        int start = offs[n], deg = cnt[n];
        for (int j = 0; j < deg; j++) {
            int slot = start + j;
            int src = srcSl[slot];
            float hs = hraw[(size_t)src * 16 + c] * scC + shC;
            const float4* ap = (const float4*)(aSl + (size_t)slot * 16);
            float4 a0 = ap[0], a1 = ap[1], a2 = ap[2], a3 = ap[3];
            B[0] += a0.x*hs; B[1] += a0.y*hs; B[2] += a0.z*hs; B[3] += a0.w*hs;
            B[4] += a1.x*hs; B[5] += a1.y*hs; B[6] += a1.z*hs; B[7] += a1.w*hs;
            B[8] += a2.x*hs; B[9] += a2.y*hs; B[10] += a2.z*hs; B[11] += a2.w*hs;
            B[12] += a3.x*hs; B[13] += a3.y*hs; B[14] += a3.z*hs; B[15] += a3.w*hs;
            B[16] += hs;
        }
    }
    float* bg = bm + g * 340;
    #pragma unroll
    for (int k = 0; k < 17; k++) bg[k * 20 + c] = B[k];
    __syncthreads();

    float part = 0.f;
    #pragma unroll
    for (int k = 0; k < 16; k++) {
        const float* wr = w2 + k * 256 + c;
        const float4* bp = (const float4*)(bg + k * 20);
        float4 b0 = bp[0], b1 = bp[1], b2v = bp[2], b3 = bp[3];
        part += b0.x*wr[0]   + b0.y*wr[16]  + b0.z*wr[32]  + b0.w*wr[48]
              + b1.x*wr[64]  + b1.y*wr[80]  + b1.z*wr[96]  + b1.w*wr[112]
              + b2v.x*wr[128]+ b2v.y*wr[144]+ b2v.z*wr[160]+ b2v.w*wr[176]
              + b3.x*wr[192] + b3.y*wr[208] + b3.z*wr[224] + b3.w*wr[240];
    }
    {
        const float* wr = b2 + c;
        const float4* bp = (const float4*)(bg + 16 * 20);
        float4 b0 = bp[0], b1 = bp[1], b2v = bp[2], b3 = bp[3];
        part += b0.x*wr[0]   + b0.y*wr[16]  + b0.z*wr[32]  + b0.w*wr[48]
              + b1.x*wr[64]  + b1.y*wr[80]  + b1.z*wr[96]  + b1.w*wr[112]
              + b2v.x*wr[128]+ b2v.y*wr[144]+ b2v.z*wr[160]+ b2v.w*wr[176]
              + b3.x*wr[192] + b3.y*wr[208] + b3.z*wr[224] + b3.w*wr[240];
    }

    float v = 0.f;
    if (n < N) {
        float hr[16];
        ld16(hraw + (size_t)n * 16, hr);
        v = cb[c] + part;
        #pragma unroll
        for (int j = 0; j < 16; j++) {
            float hv = hr[j];
            if (BNPREV) hv = hv * scsh[j] + scsh[16 + j];
            v += hv * root[j * 16 + c];
        }
        v = fmaxf(v, 0.f);
        hout[(size_t)n * 16 + c] = v;
    }
    __syncthreads();
    bm[tid] = v; bm[256 + tid] = v * v;
    __syncthreads();
    #pragma unroll
    for (int s = 128; s >= 16; s >>= 1) {
        if (tid < s) { bm[tid] += bm[tid + s]; bm[256 + tid] += bm[256 + tid + s]; }
        __syncthreads();
    }
    if (tid < 16) {
        atomicAdd(&statsCur[tid], bm[tid]);
        atomicAdd(&statsCur[16 + tid], bm[256 + tid]);
    }
}

// ---------------- mu / logvar / reparameterize (BN of layer 4 inlined) ----------------
__global__ __launch_bounds__(256) void k_z(
    const float* __restrict__ hraw, const float* __restrict__ stats4,
    const float* __restrict__ g4, const float* __restrict__ be4,
    const float* __restrict__ mu_w, const float* __restrict__ mu_b,
    const float* __restrict__ lv_w, const float* __restrict__ lv_b,
    const float* __restrict__ eps, float* __restrict__ z, int N, float invN)
{
    __shared__ float scsh[32];
    int tid = threadIdx.x;
    if (tid < 16) {
        float m = stats4[tid] * invN;
        float var = stats4[16 + tid] * invN - m * m;
        float sc = g4[tid] * rsqrtf(var + 1e-5f);
        scsh[tid] = sc;
        scsh[16 + tid] = be4[tid] - m * sc;
    }
    __syncthreads();
    int t = blockIdx.x * 256 + tid;
    if (t >= N * 16) return;
    int n = t >> 4, o = t & 15;
    float hr[16];
    ld16(hraw + (size_t)n * 16, hr);
    float mu = mu_b[o], lv = lv_b[o];
    #pragma unroll
    for (int j = 0; j < 16; j++) {
        float hv = hr[j] * scsh[j] + scsh[16 + j];
        mu += hv * mu_w[j * 16 + o];
        lv += hv * lv_w[j * 16 + o];
    }
    lv = fminf(lv, 10.f);
    z[t] = mu + eps[t] * expf(0.5f * lv);
}

// ---------------- decoder weight pre-swizzle to MFMA fragment order (bf16) ----------------
// k-slot map (used consistently for A and B, so any HW k-permutation cancels):
//   K=64 layers: sigma(g,kt,j) = 16*(2*kt + (j>>2)) + 4*g + (j&3)
//   K=32 layer0: sigma0(g,j)   = 8*g + j
// A-frag (weights, transposed): lane holds row = out_ch = 16*mt + c, slots j.
__global__ void k_wprep(const float* __restrict__ dw0, const float* __restrict__ dw1,
                        const float* __restrict__ dw2, const float* __restrict__ dw3,
                        const float* __restrict__ dw4, unsigned short* __restrict__ wfrag)
{
    int tid = blockIdx.x * 256 + threadIdx.x;
    if (tid >= 1920) return;
    int f = tid >> 6, lane = tid & 63, g = lane >> 4, c = lane & 15;
    float v[8];
    if (f < 4) {
        int mt = f;
        #pragma unroll
        for (int j = 0; j < 8; j++) v[j] = dw0[(8*g + j) * 64 + 16*mt + c];
    } else if (f < 28) {
        int fl = f - 4;
        const float* W = (fl >> 3) == 0 ? dw1 : ((fl >> 3) == 1 ? dw2 : dw3);
        int mt = (fl & 7) >> 1, kt = fl & 1;
        #pragma unroll
        for (int j = 0; j < 8; j++) {
            int in = 16*(2*kt + (j>>2)) + 4*g + (j&3);
            v[j] = W[in * 64 + 16*mt + c];
        }
    } else {
        int kt = f - 28;
        #pragma unroll
        for (int j = 0; j < 8; j++) {
            int in = 16*(2*kt + (j>>2)) + 4*g + (j&3);
            v[j] = (c < 8) ? dw4[in * 8 + c] : 0.f;
        }
    }
    unsigned short* o = wfrag + (size_t)tid * 8;
    #pragma unroll
    for (int j = 0; j < 8; j++) o[j] = f2bf(v[j]);
}

// ---------------- MFMA decoder: transposed GEMMs, in-register inter-layer repack ----------------
#define REPACK() do { \
    float av[16]; \
    _Pragma("unroll") for (int mt = 0; mt < 4; mt++) { \
        _Pragma("unroll") for (int r = 0; r < 4; r++) av[mt*4 + r] = acc[mt][r]; } \
    _Pragma("unroll") for (int kt = 0; kt < 2; kt++) { \
        _Pragma("unroll") for (int j = 0; j < 8; j++) \
            a2[kt][j] = (short)f2bf(fmaxf(av[(2*kt + (j>>2))*4 + (j&3)], 0.f)); } \
} while (0)

#define DENSE(WF, DB) do { \
    _Pragma("unroll") for (int mt = 0; mt < 4; mt++) acc[mt] = *(const f32x4*)((DB) + 16*mt + 4*g); \
    _Pragma("unroll") for (int mt = 0; mt < 4; mt++) acc[mt] = MFMA16(WF[mt][0], a2[0], acc[mt]); \
    _Pragma("unroll") for (int mt = 0; mt < 4; mt++) acc[mt] = MFMA16(WF[mt][1], a2[1], acc[mt]); \
    REPACK(); \
} while (0)

__global__ __launch_bounds__(256) void k_dec(
    const float* __restrict__ z, const int* __restrict__ ei,
    const unsigned short* __restrict__ wfrag,
    const float* __restrict__ db0, const float* __restrict__ db1,
    const float* __restrict__ db2, const float* __restrict__ db3,
    const float* __restrict__ db4,
    float* __restrict__ out, int E, int T, int totalTiles)
{
    int wid = blockIdx.x * 4 + (threadIdx.x >> 6);
    int lane = threadIdx.x & 63;
    int g = lane >> 4, c = lane & 15;
    int t0 = wid * T;
    if (t0 >= totalTiles) return;
    int t1 = min(t0 + T, totalTiles);

    // hoist all weight fragments (30 x 16B per lane, uniform-per-lane addresses -> L1/L2)
    const short8* wf = (const short8*)wfrag;
    short8 w0f[4], wfa[4][2], wfb[4][2], wfc[4][2], w4f[2];
    #pragma unroll
    for (int mt = 0; mt < 4; mt++) w0f[mt] = wf[mt * 64 + lane];
    #pragma unroll
    for (int mt = 0; mt < 4; mt++) {
        #pragma unroll
        for (int kt = 0; kt < 2; kt++) {
            wfa[mt][kt] = wf[(4  + mt*2 + kt) * 64 + lane];
            wfb[mt][kt] = wf[(12 + mt*2 + kt) * 64 + lane];
            wfc[mt][kt] = wf[(20 + mt*2 + kt) * 64 + lane];
        }
    }
    w4f[0] = wf[28 * 64 + lane];
    w4f[1] = wf[29 * 64 + lane];

    int eiOfs = (g < 2) ? 0 : E;
    int zofs = (g & 1) * 8;

    // software pipeline: zv = z for tile t (ready), node_n = node for tile t+1
    int node = ei[eiOfs + min(t0 * 16 + c, E - 1)];
    f32x4 zv0 = *(const f32x4*)(z + (size_t)node * 16 + zofs);
    f32x4 zv1 = *(const f32x4*)(z + (size_t)node * 16 + zofs + 4);
    int node_n = 0;
    if (t0 + 1 < t1) node_n = ei[eiOfs + min((t0 + 1) * 16 + c, E - 1)];

    for (int t = t0; t < t1; ++t) {
        f32x4 zn0 = {0.f,0.f,0.f,0.f}, zn1 = {0.f,0.f,0.f,0.f};
        if (t + 1 < t1) {
            zn0 = *(const f32x4*)(z + (size_t)node_n * 16 + zofs);
            zn1 = *(const f32x4*)(z + (size_t)node_n * 16 + zofs + 4);
        }
        int node_nn = 0;
        if (t + 2 < t1) node_nn = ei[eiOfs + min((t + 2) * 16 + c, E - 1)];

        // layer 0: K=32 (z_src ++ z_dst), act slot j -> channel 8g+j
        short8 af0;
        #pragma unroll
        for (int j = 0; j < 4; j++) {
            af0[j]     = (short)f2bf(zv0[j]);
            af0[4 + j] = (short)f2bf(zv1[j]);
        }
        f32x4 acc[4];
        short8 a2[2];
        #pragma unroll
        for (int mt = 0; mt < 4; mt++) acc[mt] = *(const f32x4*)(db0 + 16*mt + 4*g);
        #pragma unroll
        for (int mt = 0; mt < 4; mt++) acc[mt] = MFMA16(w0f[mt], af0, acc[mt]);
        REPACK();

        DENSE(wfa, db1);
        DENSE(wfb, db2);
        DENSE(wfc, db3);

        // final 64 -> 8 (rows 8..15 are zero-padded weights)
        f32x4 o4;
        if (g < 2) o4 = *(const f32x4*)(db4 + 4*g);
        else { o4[0]=0.f; o4[1]=0.f; o4[2]=0.f; o4[3]=0.f; }
        o4 = MFMA16(w4f[0], a2[0], o4);
        o4 = MFMA16(w4f[1], a2[1], o4);

        int e = t * 16 + c;
        if (g < 2 && e < E) *(f32x4*)(out + (size_t)e * 8 + 4*g) = o4;

        zv0 = zn0; zv1 = zn1; node_n = node_nn;
    }
}

// ---------------- launch ----------------
extern "C" void kernel_launch(void* const* d_in, const int* in_sizes, int n_in,
                              void* d_out, int out_size, void* d_ws, size_t ws_size,
                              hipStream_t stream)
{
    const float* x   = (const float*)d_in[0];
    const int*   ei  = (const int*)d_in[1];
    const float* ea  = (const float*)d_in[2];
    const float* eps = (const float*)d_in[3];
    const float* w1  = (const float*)d_in[4];
    const float* b1  = (const float*)d_in[5];
    const float* w2  = (const float*)d_in[6];
    const float* b2  = (const float*)d_in[7];
    const float* root[4]; const float* cb[4]; const float* g[4]; const float* be[4];
    for (int l = 0; l < 4; l++) {
        root[l] = (const float*)d_in[8 + 4*l];
        cb[l]   = (const float*)d_in[9 + 4*l];
        g[l]    = (const float*)d_in[10 + 4*l];
        be[l]   = (const float*)d_in[11 + 4*l];
    }
    const float* mu_w = (const float*)d_in[24];
    const float* mu_b = (const float*)d_in[25];
    const float* lv_w = (const float*)d_in[26];
    const float* lv_b = (const float*)d_in[27];
    const float* dw[5]; const float* db[5];
    for (int i = 0; i < 5; i++) {
        dw[i] = (const float*)d_in[28 + 2*i];
        db[i] = (const float*)d_in[29 + 2*i];
    }
    float* out = (float*)d_out;

    int N = in_sizes[0] / 16;
    int E = in_sizes[2] / 8;
    float invN = 1.0f / N;

    // ---- workspace layout ----
    int*   cnt      = (int*)d_ws;                 // N
    int*   cursor   = cnt + N;                    // N
    float* statsAll = (float*)(cursor + N);       // 128 (4 layers x 32)
    int*   offs     = (int*)(statsAll + 128);     // N
    int*   bsum     = offs + N;                   // 256
    int*   slotOf   = bsum + 256;                 // E
    int*   srcSl    = slotOf + E;                 // E
    float* aSl      = (float*)(srcSl + E);        // E*16
    float* hA       = aSl + (size_t)E * 16;       // N*16
    float* hB       = hA + (size_t)N * 16;        // N*16
    float* zbuf     = hB + (size_t)N * 16;        // N*16
    unsigned short* wfrag = (unsigned short*)(zbuf + (size_t)N * 16); // 15360

    int nbScan = (N + 255) / 256;                 // <=256 blocks

    hipMemsetAsync(cnt, 0, ((size_t)2 * N + 128) * sizeof(int), stream);

    // ---- decoder weight pre-swizzle (independent of graph pipeline) ----
    k_wprep<<<8, 256, 0, stream>>>(dw[0], dw[1], dw[2], dw[3], dw[4], wfrag);

    // ---- dst-CSR ----
    k_count<<<(E + 255) / 256, 256, 0, stream>>>(ei, cnt, E);
    k_scanA<<<nbScan, 256, 0, stream>>>(cnt, offs, bsum, N);
    k_scanB<<<1, 256, 0, stream>>>(bsum, nbScan);
    k_scanC<<<nbScan, 256, 0, stream>>>(offs, bsum, N);
    k_fillD<<<(E + 255) / 256, 256, 0, stream>>>(ei, offs, cursor, slotOf, srcSl, E);

    // ---- edge MLP once (layer-independent) ----
    k_a<<<(E + 255) / 256, 256, 0, stream>>>(ea, w1, b1, slotOf, aSl, E);

    int nbF = (N + 15) / 16;
    k_fuse<0><<<nbF, 256, 0, stream>>>(x,  nullptr,      nullptr, nullptr,
                                       offs, cnt, srcSl, aSl, w2, b2,
                                       root[0], cb[0], hA, statsAll + 0,  N, invN);
    k_fuse<1><<<nbF, 256, 0, stream>>>(hA, statsAll + 0,  g[0], be[0],
                                       offs, cnt, srcSl, aSl, w2, b2,
                                       root[1], cb[1], hB, statsAll + 32, N, invN);
    k_fuse<1><<<nbF, 256, 0, stream>>>(hB, statsAll + 32, g[1], be[1],
                                       offs, cnt, srcSl, aSl, w2, b2,
                                       root[2], cb[2], hA, statsAll + 64, N, invN);
    k_fuse<1><<<nbF, 256, 0, stream>>>(hA, statsAll + 64, g[2], be[2],
                                       offs, cnt, srcSl, aSl, w2, b2,
                                       root[3], cb[3], hB, statsAll + 96, N, invN);

    k_z<<<(N * 16 + 255) / 256, 256, 0, stream>>>(hB, statsAll + 96, g[3], be[3],
                                                  mu_w, mu_b, lv_w, lv_b, eps, zbuf, N, invN);

    // ---- MFMA decoder ----
    int totalTiles = (E + 15) >> 4;               // 50000
    int T = (totalTiles + 4095) / 4096;           // ~13 tiles per wave
    int wavesUsed = (totalTiles + T - 1) / T;
    int blocks = (wavesUsed + 3) / 4;
    k_dec<<<blocks, 256, 0, stream>>>(zbuf, ei, wfrag,
        db[0], db[1], db[2], db[3], db[4], out, E, T, totalTiles);
}